// Round 12
// baseline (192.638 us; speedup 1.0000x reference)
//
#include <hip/hip_runtime.h>
#include <hip/hip_bf16.h>

// MoE MLP (top-2 of 8 experts), T=4096 tokens, D=1024, W=1024.
// R18: R17 frame + COUNTED-VMCNT double-buffered GEMM K-loop (T4, the one
//      big measured lever never properly tried: R9's dbuf used __syncthreads
//      whose implicit vmcnt(0) drain IS the m97-ceiling stall; m218 measured
//      counted-vs-drain = +38-73%). Pattern (HK/m201-verified, cross-wave
//      safe): issue next-tile STAGE into buf^1, `s_waitcnt vmcnt(8)` (waits
//      out the 8 OLDEST = current tile, per m135), raw s_barrier -- each wave
//      certifies its own loads before arriving, so post-barrier the whole
//      tile is in LDS while 8 next-tile loads stay in flight ACROSS the
//      barrier. 64KB LDS, lb(256,2) (R14: occupancy 2 vs 4 is time-neutral
//      here, so dbuf's occupancy cost is ~free).
// Frame: XCD-aligned w1t in pre + vectorized router (R17), k2 = {blk0 ballot
//      lists || blks 1-512 w2t XCD-aligned} (R16), 128x128 BK=64 granule-XOR
//      swizzle GEMM bodies (R8/R10), grid-strided combine, CAP=1536.

#define T_TOKENS 4096
#define DD 1024
#define EE 8
#define WW 1024
#define CAP 1536              // per-expert capacity (expected ~1024, sigma ~28)
#define BM 128
#define BN 128
#define BK 64
#define MT (CAP / BM)         // 12 m-tiles max per expert
#define NT (WW / BN)          // 8 n-tiles
#define GEMM_BLOCKS (EE * MT * NT)  // 768
#define TR1_BLOCKS 512        // w1 transpose blocks (128x128 tiles, in pre)
#define TLD 132               // LDS transpose tile row stride (shorts), pad=4

typedef short bf16x8 __attribute__((ext_vector_type(8)));
typedef float f32x4 __attribute__((ext_vector_type(4)));

__device__ __forceinline__ void gload_lds16(const void* g, void* l) {
  __builtin_amdgcn_global_load_lds((__attribute__((address_space(1))) void*)(g),
                                   (__attribute__((address_space(3))) void*)(l),
                                   16, 0, 0);
}

__device__ __forceinline__ float bf2f(unsigned short u) {
  union { unsigned int i; float f; } v; v.i = (unsigned int)u << 16; return v.f;
}

__device__ __forceinline__ unsigned short f2bf_u(float f) {
  __hip_bfloat16 h = __float2bfloat16(f);
  union { __hip_bfloat16 h; unsigned short u; } c; c.h = h; return c.u;
}

// ---- 128x128 fp32->bf16 transpose tile through LDS, 256 threads (R10) ----
__device__ __forceinline__ void transpose_tile_128(
    const float* __restrict__ src, long src_ld, long r0, long c0,
    unsigned short* __restrict__ dst, long dst_ld, unsigned short* lds)
{
  int tid = threadIdx.x;
  int cq = tid & 31;            // covers 4 src cols
  int rb = tid >> 5;            // row base 0..7
#pragma unroll
  for (int i = 0; i < 16; i++) {
    int r = rb + i * 8;
    f32x4 v = *(const f32x4*)(src + (r0 + r) * src_ld + c0 + cq * 4);
#pragma unroll
    for (int j = 0; j < 4; j++)
      lds[(cq * 4 + j) * TLD + r] = f2bf_u(v[j]);
  }
  __syncthreads();
#pragma unroll
  for (int it = 0; it < 8; it++) {
    int slot = it * 256 + tid;
    int c = slot >> 4;          // dst row within tile
    int m = slot & 15;          // 8-elem chunk within row
    const unsigned short* p = lds + (size_t)c * TLD + m * 8;
    uint2 lo = *(const uint2*)(p);
    uint2 hi = *(const uint2*)(p + 4);
    uint4 o; o.x = lo.x; o.y = lo.y; o.z = hi.x; o.w = hi.y;
    *(uint4*)(dst + (c0 + c) * dst_ld + r0 + m * 8) = o;
  }
}

// ---------------- pre: w1 transpose (XCD-aligned) + vectorized router -------
__global__ __launch_bounds__(256) void pre_kernel(
    const float* __restrict__ w1, const float* __restrict__ x,
    const float* __restrict__ rw,
    __hip_bfloat16* __restrict__ w1t, __hip_bfloat16* __restrict__ xb,
    int* __restrict__ sel, float* __restrict__ wpair)
{
  __shared__ unsigned short lds_t[128 * TLD];   // 33792 B
  int b = blockIdx.x;
  if (b < TR1_BLOCKS) {
    int e = b & 7;
    int t = b >> 3;             // 0..63
    int bn = e * 8 + (t >> 3);  // dst row tile (expert slab rows e*1024..)
    int bd = t & 7;             // dst col tile
    transpose_tile_128(w1, EE * WW, (long)bd * 128, (long)bn * 128,
                       (unsigned short*)w1t, DD, lds_t);
  } else {
    // router: one wave per token, f32x4 x / rw loads, packed bf16x4 stores
    int lane = threadIdx.x & 63;
    int wave = threadIdx.x >> 6;
    int t = (b - TR1_BLOCKS) * 4 + wave;
    const float* xrow = x + (size_t)t * DD;
    unsigned short* xbrow = (unsigned short*)xb + (size_t)t * DD;
    float acc[EE];
#pragma unroll
    for (int e = 0; e < EE; e++) acc[e] = 0.f;
#pragma unroll
    for (int i = 0; i < DD / 256; i++) {        // 4 iterations
      int d = lane * 4 + i * 256;
      f32x4 xv = *(const f32x4*)(xrow + d);
      union { unsigned short u[4]; ushort4 v; } pk;
#pragma unroll
      for (int j = 0; j < 4; j++) pk.u[j] = f2bf_u(xv[j]);
      *(ushort4*)(xbrow + d) = pk.v;            // fused x -> bf16
#pragma unroll
      for (int e = 0; e < EE; e++) {
        f32x4 rv = *(const f32x4*)(rw + e * DD + d);
        acc[e] += xv[0] * rv[0] + xv[1] * rv[1] + xv[2] * rv[2] + xv[3] * rv[3];
      }
    }
#pragma unroll
    for (int e = 0; e < EE; e++) {
#pragma unroll
      for (int off = 32; off > 0; off >>= 1)
        acc[e] += __shfl_down(acc[e], off, 64);
    }
    if (lane == 0) {
      float p[EE];
#pragma unroll
      for (int e = 0; e < EE; e++) p[e] = 1.f / (1.f + expf(-acc[e]));
      int e0 = 0; float b0 = p[0];
      for (int e = 1; e < EE; e++) if (p[e] > b0) { b0 = p[e]; e0 = e; }
      int e1 = -1; float b1 = -1.f;
      for (int e = 0; e < EE; e++) {
        if (e == e0) continue;
        if (p[e] > b1) { b1 = p[e]; e1 = e; }
      }
      float s = b0 + b1 + 1e-20f;
      sel[t] = e0 | (e1 << 8);
      wpair[2 * t]     = b0 / s;
      wpair[2 * t + 1] = b1 / s;
    }
  }
}

// ------- k2: block 0 = ballot list build; blocks 1..512 = w2 transpose ------
__global__ __launch_bounds__(1024) void lists_w2t_kernel(
    const int* __restrict__ sel, int* __restrict__ counts,
    int* __restrict__ idx, int* __restrict__ tslot,
    const float* __restrict__ w2, __hip_bfloat16* __restrict__ w2t)
{
  __shared__ __attribute__((aligned(16))) unsigned short lds_t[128 * TLD];
  __shared__ int lcnt[EE];
  int bid = blockIdx.x;
  int tid = threadIdx.x;
  if (bid == 0) {
    int lane = tid & 63;
    if (tid < EE) lcnt[tid] = 0;
    __syncthreads();
    unsigned long long lower = (1ull << lane) - 1;
#pragma unroll
    for (int j = 0; j < T_TOKENS / 1024; j++) {
      int t = j * 1024 + tid;
      int s = sel[t];
      int e0 = s & 0xff, e1 = (s >> 8) & 0xff;
      int slot0 = 0, slot1 = 0;
#pragma unroll
      for (int e = 0; e < EE; e++) {
        unsigned long long m0 = __ballot(e0 == e);
        unsigned long long m1 = __ballot(e1 == e);
        int c0 = __popcll(m0), c1 = __popcll(m1);
        int base = 0;
        if (lane == 0 && (c0 + c1) > 0) base = atomicAdd(&lcnt[e], c0 + c1);
        base = __shfl(base, 0, 64);
        if (e0 == e) slot0 = base + __popcll(m0 & lower);
        if (e1 == e) slot1 = base + c0 + __popcll(m1 & lower);
      }
      int p0 = e0 * CAP + slot0, p1 = e1 * CAP + slot1;
      idx[p0] = t; idx[p1] = t;
      tslot[2 * t] = p0; tslot[2 * t + 1] = p1;
    }
    __syncthreads();
    if (tid < EE) counts[tid] = lcnt[tid];
  } else {
    // ---- w2 transpose: expert slice [W,D] -> w2t[e] [D,W], e = bid&7 ----
    int e = bid & 7;
    int t2 = (bid - 1) >> 3;        // 0..63
    const float* src = w2 + (long)e * WW * DD;
    unsigned short* dst = (unsigned short*)(w2t + (long)e * DD * WW);
    long r0 = (long)(t2 >> 3) * 128;   // W dim (src row / dst col)
    long c0 = (long)(t2 & 7) * 128;    // D dim (src col / dst row)
    int cq = tid & 31;            // 4 src cols
    int row = tid >> 5;           // 0..31
#pragma unroll
    for (int i = 0; i < 4; i++) {
      int r = row + i * 32;
      f32x4 v = *(const f32x4*)(src + (r0 + r) * DD + c0 + cq * 4);
#pragma unroll
      for (int j = 0; j < 4; j++)
        lds_t[(cq * 4 + j) * TLD + r] = f2bf_u(v[j]);
    }
    __syncthreads();
#pragma unroll
    for (int it = 0; it < 2; it++) {
      int slot = it * 1024 + tid;
      int c = slot >> 4;          // dst row within tile
      int m = slot & 15;          // 8-elem chunk within row
      const unsigned short* p = lds_t + (size_t)c * TLD + m * 8;
      uint2 lo = *(const uint2*)(p);
      uint2 hi = *(const uint2*)(p + 4);
      uint4 o; o.x = lo.x; o.y = lo.y; o.z = hi.x; o.w = hi.y;
      *(uint4*)(dst + (c0 + c) * WW + r0 + m * 8) = o;
    }
  }
}

// ---------------- grouped GEMM1: act = relu(gather(xb) @ W1_e)^2 ------------
// 768 blocks, 128x128 tile, BK=64, counted-vmcnt dbuf K-loop.
__global__ __launch_bounds__(256, 2) void gemm1_kernel(
    const __hip_bfloat16* __restrict__ xb, const __hip_bfloat16* __restrict__ w1t,
    const int* __restrict__ counts, const int* __restrict__ idx,
    __hip_bfloat16* __restrict__ act)
{
  // dbuf: buf p at p*32768 (As), p*32768+16384 (Bs)
  __shared__ __attribute__((aligned(16))) char smem[65536];
  int bid = blockIdx.x;
  int e = bid & 7;
  int i = bid >> 3;
  int mt = i >> 3, nt = i & 7;
  int n_e = counts[e];
  if (mt * BM >= n_e) return;

  int tid = threadIdx.x;
  int lane = tid & 63;
  int wave = __builtin_amdgcn_readfirstlane(tid >> 6);
  int wm = (wave >> 1) * 64, wn = (wave & 1) * 64;
  int m16 = lane & 15, qd = lane >> 4;

  const __hip_bfloat16* gA[4];
  const __hip_bfloat16* gB[4];
#pragma unroll
  for (int i2 = 0; i2 < 4; i2++) {
    int s = i2 * 256 + tid;
    int r = s >> 3;
    int q = (s & 7) ^ (r & 7);
    int rowA = mt * BM + r;
    int slot = rowA < n_e ? rowA : n_e - 1;   // clamp tail rows to valid slot
    int tok = idx[e * CAP + slot];
    gA[i2] = xb + (size_t)tok * DD + q * 8;
    gB[i2] = w1t + ((size_t)e * WW + nt * BN + r) * DD + q * 8;
  }
  int ldsOff[4];
#pragma unroll
  for (int i2 = 0; i2 < 4; i2++) ldsOff[i2] = (i2 * 256 + wave * 64) * 8;

  int aoff[4][2], boff[4][2];
#pragma unroll
  for (int mi = 0; mi < 4; mi++) {
    int r = wm + mi * 16 + m16;
#pragma unroll
    for (int h = 0; h < 2; h++)
      aoff[mi][h] = (r * 8 + ((qd + h * 4) ^ (r & 7))) * 8;
  }
#pragma unroll
  for (int ni = 0; ni < 4; ni++) {
    int r = wn + ni * 16 + m16;
#pragma unroll
    for (int h = 0; h < 2; h++)
      boff[ni][h] = (r * 8 + ((qd + h * 4) ^ (r & 7))) * 8;
  }

  f32x4 zero = {0.f, 0.f, 0.f, 0.f};
  f32x4 acc[4][4];
#pragma unroll
  for (int mi = 0; mi < 4; mi++)
#pragma unroll
    for (int ni = 0; ni < 4; ni++) acc[mi][ni] = zero;

  // prologue: stage tile 0 into buf 0 (8 loads/wave)
#pragma unroll
  for (int i2 = 0; i2 < 4; i2++) {
    gload_lds16(gA[i2], (short*)smem + ldsOff[i2]);
    gload_lds16(gB[i2], (short*)(smem + 16384) + ldsOff[i2]);
  }

  int kk = 0;
  for (int k0 = 0; k0 < DD; k0 += BK, kk ^= 1) {
    if (k0 + BK < DD) {
      // stage next tile into buf^1; its 8 loads stay in flight across barrier
      char* nb = smem + (kk ^ 1) * 32768;
#pragma unroll
      for (int i2 = 0; i2 < 4; i2++) {
        gload_lds16(gA[i2] + k0 + BK, (short*)nb + ldsOff[i2]);
        gload_lds16(gB[i2] + k0 + BK, (short*)(nb + 16384) + ldsOff[i2]);
      }
      // wait out the 8 OLDEST (current tile); 8 newest remain in flight
      asm volatile("s_waitcnt vmcnt(8)" ::: "memory");
    } else {
      asm volatile("s_waitcnt vmcnt(0)" ::: "memory");
    }
    __builtin_amdgcn_s_barrier();     // all waves certified their loads
    asm volatile("" ::: "memory");    // no LDS read hoists above barrier
    short* As = (short*)(smem + kk * 32768);
    short* Bs = (short*)(smem + kk * 32768 + 16384);
#pragma unroll
    for (int h = 0; h < 2; h++) {
      bf16x8 af[4], bfr[4];
#pragma unroll
      for (int mi = 0; mi < 4; mi++) af[mi] = *(const bf16x8*)(As + aoff[mi][h]);
#pragma unroll
      for (int ni = 0; ni < 4; ni++) bfr[ni] = *(const bf16x8*)(Bs + boff[ni][h]);
#pragma unroll
      for (int mi = 0; mi < 4; mi++)
#pragma unroll
        for (int ni = 0; ni < 4; ni++)
          acc[mi][ni] = __builtin_amdgcn_mfma_f32_16x16x32_bf16(
              af[mi], bfr[ni], acc[mi][ni], 0, 0, 0);
    }
    asm volatile("" ::: "memory");    // LDS reads done before barrier
    __builtin_amdgcn_s_barrier();     // buf safe to overwrite next iter
    asm volatile("" ::: "memory");
  }

  // epilogue: relu^2 -> bf16 act[(e*CAP + slot)][col]
#pragma unroll
  for (int mi = 0; mi < 4; mi++) {
#pragma unroll
    for (int reg = 0; reg < 4; reg++) {
      int rowt = mt * BM + wm + mi * 16 + qd * 4 + reg;
      if (rowt < n_e) {
#pragma unroll
        for (int ni = 0; ni < 4; ni++) {
          float v = acc[mi][ni][reg];
          v = v > 0.f ? v * v : 0.f;
          int col = nt * BN + wn + ni * 16 + m16;
          act[((size_t)e * CAP + rowt) * WW + col] = __float2bfloat16(v);
        }
      }
    }
  }
}

// ---------------- grouped GEMM2: y = act @ W2_e (counted-vmcnt dbuf) --------
__global__ __launch_bounds__(256, 2) void gemm2_kernel(
    const __hip_bfloat16* __restrict__ act, const __hip_bfloat16* __restrict__ w2t,
    const int* __restrict__ counts, __hip_bfloat16* __restrict__ y)
{
  __shared__ __attribute__((aligned(16))) char smem[65536];
  int bid = blockIdx.x;
  int e = bid & 7;
  int i = bid >> 3;
  int mt = i >> 3, nt = i & 7;
  int n_e = counts[e];
  if (mt * BM >= n_e) return;

  int tid = threadIdx.x;
  int lane = tid & 63;
  int wave = __builtin_amdgcn_readfirstlane(tid >> 6);
  int wm = (wave >> 1) * 64, wn = (wave & 1) * 64;
  int m16 = lane & 15, qd = lane >> 4;

  const __hip_bfloat16* gA[4];
  const __hip_bfloat16* gB[4];
#pragma unroll
  for (int i2 = 0; i2 < 4; i2++) {
    int s = i2 * 256 + tid;
    int r = s >> 3;
    int q = (s & 7) ^ (r & 7);
    // rows >= n_e: poison bytes, but row-isolated in MFMA -> discarded rows only
    gA[i2] = act + ((size_t)e * CAP + mt * BM + r) * WW + q * 8;
    gB[i2] = w2t + ((size_t)e * DD + nt * BN + r) * WW + q * 8;
  }
  int ldsOff[4];
#pragma unroll
  for (int i2 = 0; i2 < 4; i2++) ldsOff[i2] = (i2 * 256 + wave * 64) * 8;

  int aoff[4][2], boff[4][2];
#pragma unroll
  for (int mi = 0; mi < 4; mi++) {
    int r = wm + mi * 16 + m16;
#pragma unroll
    for (int h = 0; h < 2; h++)
      aoff[mi][h] = (r * 8 + ((qd + h * 4) ^ (r & 7))) * 8;
  }
#pragma unroll
  for (int ni = 0; ni < 4; ni++) {
    int r = wn + ni * 16 + m16;
#pragma unroll
    for (int h = 0; h < 2; h++)
      boff[ni][h] = (r * 8 + ((qd + h * 4) ^ (r & 7))) * 8;
  }

  f32x4 zero = {0.f, 0.f, 0.f, 0.f};
  f32x4 acc[4][4];
#pragma unroll
  for (int mi = 0; mi < 4; mi++)
#pragma unroll
    for (int ni = 0; ni < 4; ni++) acc[mi][ni] = zero;

#pragma unroll
  for (int i2 = 0; i2 < 4; i2++) {
    gload_lds16(gA[i2], (short*)smem + ldsOff[i2]);
    gload_lds16(gB[i2], (short*)(smem + 16384) + ldsOff[i2]);
  }

  int kk = 0;
  for (int k0 = 0; k0 < WW; k0 += BK, kk ^= 1) {
    if (k0 + BK < WW) {
      char* nb = smem + (kk ^ 1) * 32768;
#pragma unroll
      for (int i2 = 0; i2 < 4; i2++) {
        gload_lds16(gA[i2] + k0 + BK, (short*)nb + ldsOff[i2]);
        gload_lds16(gB[i2] + k0 + BK, (short*)(nb + 16384) + ldsOff[i2]);
      }
      asm volatile("s_waitcnt vmcnt(8)" ::: "memory");
    } else {
      asm volatile("s_waitcnt vmcnt(0)" ::: "memory");
    }
    __builtin_amdgcn_s_barrier();
    asm volatile("" ::: "memory");
    short* As = (short*)(smem + kk * 32768);
    short* Bs = (short*)(smem + kk * 32768 + 16384);
#pragma unroll
    for (int h = 0; h < 2; h++) {
      bf16x8 af[4], bfr[4];
#pragma unroll
      for (int mi = 0; mi < 4; mi++) af[mi] = *(const bf16x8*)(As + aoff[mi][h]);
#pragma unroll
      for (int ni = 0; ni < 4; ni++) bfr[ni] = *(const bf16x8*)(Bs + boff[ni][h]);
#pragma unroll
      for (int mi = 0; mi < 4; mi++)
#pragma unroll
        for (int ni = 0; ni < 4; ni++)
          acc[mi][ni] = __builtin_amdgcn_mfma_f32_16x16x32_bf16(
              af[mi], bfr[ni], acc[mi][ni], 0, 0, 0);
    }
    asm volatile("" ::: "memory");
    __builtin_amdgcn_s_barrier();
    asm volatile("" ::: "memory");
  }

  // epilogue: raw y (routing weights applied in combine)
#pragma unroll
  for (int mi = 0; mi < 4; mi++) {
#pragma unroll
    for (int reg = 0; reg < 4; reg++) {
      int slot = mt * BM + wm + mi * 16 + qd * 4 + reg;
      if (slot < n_e) {
#pragma unroll
        for (int ni = 0; ni < 4; ni++) {
          int col = nt * BN + wn + ni * 16 + m16;
          y[((size_t)e * CAP + slot) * DD + col] = __float2bfloat16(acc[mi][ni][reg]);
        }
      }
    }
  }
}

// ---------------- combine: out[t] = w0*y[slot0] + w1*y[slot1] ----------------
__global__ __launch_bounds__(256) void combine_kernel(
    const __hip_bfloat16* __restrict__ y, const int* __restrict__ tslot,
    const float* __restrict__ wpair, float* __restrict__ out)
{
  int c = threadIdx.x * 4;
  for (int t = blockIdx.x; t < T_TOKENS; t += 512) {
    int s0 = tslot[2 * t], s1 = tslot[2 * t + 1];
    float w0 = wpair[2 * t], w1 = wpair[2 * t + 1];
    const unsigned short* yu = (const unsigned short*)y;
    ushort4 a = *(const ushort4*)(yu + (size_t)s0 * DD + c);
    ushort4 bq = *(const ushort4*)(yu + (size_t)s1 * DD + c);
    f32x4 o;
    o[0] = w0 * bf2f(a.x) + w1 * bf2f(bq.x);
    o[1] = w0 * bf2f(a.y) + w1 * bf2f(bq.y);
    o[2] = w0 * bf2f(a.z) + w1 * bf2f(bq.z);
    o[3] = w0 * bf2f(a.w) + w1 * bf2f(bq.w);
    *(f32x4*)(out + (size_t)t * DD + c) = o;
  }
}

extern "C" void kernel_launch(void* const* d_in, const int* in_sizes, int n_in,
                              void* d_out, int out_size, void* d_ws, size_t ws_size,
                              hipStream_t stream)
{
  const float* x  = (const float*)d_in[0];
  const float* rw = (const float*)d_in[1];
  const float* w1 = (const float*)d_in[2];
  const float* w2 = (const float*)d_in[3];
  float* out = (float*)d_out;

  char* ws = (char*)d_ws;
  __hip_bfloat16* xb  = (__hip_bfloat16*)ws;  ws += (size_t)T_TOKENS * DD * 2;
  __hip_bfloat16* w1t = (__hip_bfloat16*)ws;  ws += (size_t)EE * WW * DD * 2;
  __hip_bfloat16* w2t = (__hip_bfloat16*)ws;  ws += (size_t)EE * DD * WW * 2;
  __hip_bfloat16* act = (__hip_bfloat16*)ws;  ws += (size_t)EE * CAP * WW * 2;
  __hip_bfloat16* y   = (__hip_bfloat16*)ws;  ws += (size_t)EE * CAP * DD * 2;
  int*   counts = (int*)ws;                   ws += 256;
  int*   idx    = (int*)ws;                   ws += (size_t)EE * CAP * 4;
  int*   sel    = (int*)ws;                   ws += (size_t)T_TOKENS * 4;
  int*   tslot  = (int*)ws;                   ws += (size_t)T_TOKENS * 8;
  float* wpair  = (float*)ws;                 ws += (size_t)T_TOKENS * 8;

  // k1: w1 transpose (XCD-aligned, 512 blocks) + vectorized router
  pre_kernel<<<TR1_BLOCKS + T_TOKENS / 4, 256, 0, stream>>>(
      w1, x, rw, w1t, xb, sel, wpair);
  // k2: list build (block 0) hidden under w2 transpose (blocks 1..512)
  lists_w2t_kernel<<<513, 1024, 0, stream>>>(sel, counts, idx, tslot, w2, w2t);
  // k3: grouped GEMM1 (counted-vmcnt dbuf)
  gemm1_kernel<<<GEMM_BLOCKS, 256, 0, stream>>>(xb, w1t, counts, idx, act);
  // k4: grouped GEMM2 (counted-vmcnt dbuf)
  gemm2_kernel<<<GEMM_BLOCKS, 256, 0, stream>>>(act, w2t, counts, y);
  // k5: weighted combine (grid-stride, 512 blocks)
  combine_kernel<<<512, 256, 0, stream>>>(y, tslot, wpair, out);
}